// Round 1
// baseline (1199.659 us; speedup 1.0000x reference)
//
#include <hip/hip_runtime.h>
#include <stdint.h>

typedef unsigned short u16;
typedef __attribute__((ext_vector_type(8))) short s8bf;   // 8 bf16 in 4 VGPRs
typedef __attribute__((ext_vector_type(4))) float f32x4;

#define N_TOK 8192
#define DIM   1024
#define HID   4096
#define NE    8
#define MAX_SLOTS 17408   // 16384 + 8*128 worst-case padding
#define MAX_TILES 160

// ---- workspace layout (bytes) ----
#define OFF_W1T  ((size_t)0)                    // [E][HID][DIM] bf16  (transposed, n-major)
#define OFF_W2T  ((size_t)67108864)             // [E][DIM][HID] bf16
#define OFF_XB   ((size_t)134217728)            // [N_TOK][DIM] bf16
#define OFF_H    ((size_t)150994944)            // [MAX_SLOTS][HID] bf16
#define OFF_TOS  ((size_t)293601280)            // token_of_slot int[MAX_SLOTS]
#define OFF_WOS  ((size_t)293670912)            // weight_of_slot float[MAX_SLOTS]
#define OFF_TKI  ((size_t)293740544)            // topk idx int[N_TOK*2]
#define OFF_TKW  ((size_t)293806080)            // topk w  float[N_TOK*2]
#define OFF_CNT  ((size_t)293871616)            // counts int[8]
#define OFF_POF  ((size_t)293871680)            // padded offsets int[8]
#define OFF_CUR  ((size_t)293871744)            // cursors int[8]
#define OFF_NT   ((size_t)293871808)            // n_tiles int[1]
#define OFF_TE   ((size_t)293871872)            // tile_expert int[MAX_TILES]
#define OFF_TS   ((size_t)293872896)            // tile_slot0  int[MAX_TILES]

__device__ __forceinline__ u16 f2b(float v) {   // fp32 -> bf16 RNE
  union { float f; uint32_t u; } c; c.f = v;
  uint32_t u = c.u;
  return (u16)((u + 0x7FFFu + ((u >> 16) & 1u)) >> 16);
}

// ---- fp32 [R][C] -> bf16 [C][R] transpose (per expert), 32x32 LDS tiles ----
__global__ __launch_bounds__(256) void transpose_to_bf16(
    const float* __restrict__ in, u16* __restrict__ out, int R, int C) {
  __shared__ float tile[32][33];
  int tiles_c = C >> 5, tiles_r = R >> 5;
  int per = tiles_c * tiles_r;
  int e = blockIdx.x / per, t = blockIdx.x % per;
  int tr = t / tiles_c, tc = t % tiles_c;
  const float* ip = in + (size_t)e * R * C;
  u16* op = out + (size_t)e * R * C;
  int tx = threadIdx.x & 31, ty = threadIdx.x >> 5;
  #pragma unroll
  for (int i = 0; i < 4; i++)
    tile[ty + i * 8][tx] = ip[(size_t)(tr * 32 + ty + i * 8) * C + tc * 32 + tx];
  __syncthreads();
  #pragma unroll
  for (int i = 0; i < 4; i++)
    op[(size_t)(tc * 32 + ty + i * 8) * R + tr * 32 + tx] = f2b(tile[tx][ty + i * 8]);
}

// ---- x fp32 -> bf16 ----
__global__ __launch_bounds__(256) void convert_x(const float* __restrict__ x,
                                                 u16* __restrict__ xb) {
  size_t i = ((size_t)blockIdx.x * 256 + threadIdx.x) * 8;
  float4 v0 = *(const float4*)(x + i);
  float4 v1 = *(const float4*)(x + i + 4);
  u16 o[8] = {f2b(v0.x), f2b(v0.y), f2b(v0.z), f2b(v0.w),
              f2b(v1.x), f2b(v1.y), f2b(v1.z), f2b(v1.w)};
  *(uint4*)(xb + i) = *(const uint4*)o;
}

// ---- router: logits -> top2 -> renormalized weights (fp32). one wave/token ----
__global__ __launch_bounds__(256) void router_kernel(
    const float* __restrict__ x, const float* __restrict__ Wr,
    const float* __restrict__ br, int* __restrict__ tki, float* __restrict__ tkw,
    int* __restrict__ counts) {
  int wave = threadIdx.x >> 6, lane = threadIdx.x & 63;
  int t = blockIdx.x * 4 + wave;
  const float* xr = x + (size_t)t * DIM;
  float acc[8] = {0.f, 0.f, 0.f, 0.f, 0.f, 0.f, 0.f, 0.f};
  #pragma unroll
  for (int i = 0; i < 16; i++) {
    int d = lane + i * 64;
    float xv = xr[d];
    float4 wa = *(const float4*)(Wr + d * 8);
    float4 wb = *(const float4*)(Wr + d * 8 + 4);
    acc[0] += xv * wa.x; acc[1] += xv * wa.y; acc[2] += xv * wa.z; acc[3] += xv * wa.w;
    acc[4] += xv * wb.x; acc[5] += xv * wb.y; acc[6] += xv * wb.z; acc[7] += xv * wb.w;
  }
  #pragma unroll
  for (int e = 0; e < 8; e++)
    #pragma unroll
    for (int off = 32; off >= 1; off >>= 1)
      acc[e] += __shfl_xor(acc[e], off, 64);
  if (lane == 0) {
    float l[8];
    #pragma unroll
    for (int e = 0; e < 8; e++) l[e] = acc[e] + br[e];
    float l0 = -1e30f; int i0 = 0;
    #pragma unroll
    for (int e = 0; e < 8; e++) if (l[e] > l0) { l0 = l[e]; i0 = e; }
    float l1 = -1e30f; int i1 = 0;
    #pragma unroll
    for (int e = 0; e < 8; e++) if (e != i0 && l[e] > l1) { l1 = l[e]; i1 = e; }
    // renormalized top-2 softmax == 2-way softmax of top-2 logits
    float w0 = 1.f / (1.f + expf(l1 - l0));
    tki[t * 2] = i0; tki[t * 2 + 1] = i1;
    tkw[t * 2] = w0; tkw[t * 2 + 1] = 1.f - w0;
    atomicAdd(&counts[i0], 1);
    atomicAdd(&counts[i1], 1);
  }
}

// ---- plan: padded per-expert offsets + tile list ----
__global__ void plan_kernel(const int* __restrict__ counts, int* __restrict__ poff,
                            int* __restrict__ cursor, int* __restrict__ ntiles,
                            int* __restrict__ tile_e, int* __restrict__ tile_s0) {
  if (threadIdx.x == 0 && blockIdx.x == 0) {
    int po = 0, nt = 0;
    for (int e = 0; e < NE; e++) {
      poff[e] = po;
      cursor[e] = 0;
      int c = counts[e];
      int tl = (c + 127) >> 7;
      for (int j = 0; j < tl; j++) { tile_e[nt] = e; tile_s0[nt] = po + j * 128; nt++; }
      po += tl << 7;
    }
    ntiles[0] = nt;
  }
}

// ---- scatter tokens into per-expert slots ----
__global__ __launch_bounds__(256) void scatter_kernel(
    const int* __restrict__ tki, const float* __restrict__ tkw,
    const int* __restrict__ poff, int* __restrict__ cursor,
    int* __restrict__ token_of_slot, float* __restrict__ weight_of_slot) {
  int t = blockIdx.x * 256 + threadIdx.x;
  #pragma unroll
  for (int k = 0; k < 2; k++) {
    int e = tki[t * 2 + k];
    int r = atomicAdd(&cursor[e], 1);
    int s = poff[e] + r;
    token_of_slot[s] = t;
    weight_of_slot[s] = tkw[t * 2 + k];
  }
}

// ---- grouped GEMM: C[128x128] per block, 4 waves, 16x16x32 bf16 MFMA ----
// MODE 1: A = xb gathered by token_of_slot, epilogue relu(acc+b1) -> h (bf16)
// MODE 2: A = h by slot,                   epilogue (acc+b2)*w atomicAdd-> out
template <int MODE>
__global__ __launch_bounds__(256) void moe_gemm(
    const u16* __restrict__ A, const u16* __restrict__ Bt,
    const float* __restrict__ bias, u16* __restrict__ Hout,
    float* __restrict__ Out, const int* __restrict__ tile_e,
    const int* __restrict__ tile_s0, const int* __restrict__ ntiles,
    const int* __restrict__ token_of_slot, const float* __restrict__ weight_of_slot,
    int K, int N) {
  if ((int)blockIdx.x >= ntiles[0]) return;
  const int e = tile_e[blockIdx.x];
  const int slot0 = tile_s0[blockIdx.x];
  const int n0 = blockIdx.y * 128;

  __shared__ u16 lA[128 * 32];
  __shared__ u16 lB[128 * 32];

  const int tid = threadIdx.x;
  const int lane = tid & 63;
  const int wave = tid >> 6;
  const int wm = wave >> 1, wn = wave & 1;

  // staging: 512 chunks of 16B; chunk c -> row c>>2, 8 cols at (c&3)*8; lds ofs c*8 (u16)
  const int r0 = tid >> 2, r1 = r0 + 64;
  const int c8 = (tid & 3) * 8;
  int arow0, arow1;
  if (MODE == 1) {
    int t0 = token_of_slot[slot0 + r0]; arow0 = t0 < 0 ? 0 : t0;
    int t1 = token_of_slot[slot0 + r1]; arow1 = t1 < 0 ? 0 : t1;
  } else {
    arow0 = slot0 + r0; arow1 = slot0 + r1;
  }
  const u16* aP0 = A + (size_t)arow0 * K + c8;
  const u16* aP1 = A + (size_t)arow1 * K + c8;
  const u16* bE = Bt + (size_t)e * N * K;
  const u16* bP0 = bE + (size_t)(n0 + r0) * K + c8;
  const u16* bP1 = bE + (size_t)(n0 + r1) * K + c8;

  f32x4 acc[4][4];
  #pragma unroll
  for (int i = 0; i < 4; i++)
    #pragma unroll
    for (int j = 0; j < 4; j++) acc[i][j] = (f32x4){0.f, 0.f, 0.f, 0.f};

  for (int kb = 0; kb < K; kb += 32) {
    uint4 va0 = *(const uint4*)(aP0 + kb);
    uint4 va1 = *(const uint4*)(aP1 + kb);
    uint4 vb0 = *(const uint4*)(bP0 + kb);
    uint4 vb1 = *(const uint4*)(bP1 + kb);
    __syncthreads();
    *(uint4*)&lA[(size_t)tid * 8] = va0;
    *(uint4*)&lA[(size_t)(tid + 256) * 8] = va1;
    *(uint4*)&lB[(size_t)tid * 8] = vb0;
    *(uint4*)&lB[(size_t)(tid + 256) * 8] = vb1;
    __syncthreads();
    const int qk = (lane >> 4) * 8;
    s8bf af[4], bf[4];
    #pragma unroll
    for (int mt = 0; mt < 4; mt++)
      af[mt] = *(const s8bf*)&lA[(wm * 64 + mt * 16 + (lane & 15)) * 32 + qk];
    #pragma unroll
    for (int nt = 0; nt < 4; nt++)
      bf[nt] = *(const s8bf*)&lB[(wn * 64 + nt * 16 + (lane & 15)) * 32 + qk];
    #pragma unroll
    for (int mt = 0; mt < 4; mt++)
      #pragma unroll
      for (int nt = 0; nt < 4; nt++)
        acc[mt][nt] = __builtin_amdgcn_mfma_f32_16x16x32_bf16(af[mt], bf[nt],
                                                              acc[mt][nt], 0, 0, 0);
  }

  // epilogue: C/D layout col=lane&15, row=(lane>>4)*4+reg
  const int colq = lane & 15;
  const int rq = (lane >> 4) * 4;
  #pragma unroll
  for (int nt = 0; nt < 4; nt++) {
    int gcol = n0 + wn * 64 + nt * 16 + colq;
    float bv = bias[(size_t)e * N + gcol];
    #pragma unroll
    for (int mt = 0; mt < 4; mt++) {
      int rowbase = wm * 64 + mt * 16 + rq;
      #pragma unroll
      for (int r = 0; r < 4; r++) {
        int slot = slot0 + rowbase + r;
        float v = acc[mt][nt][r] + bv;
        if (MODE == 1) {
          v = fmaxf(v, 0.f);
          Hout[(size_t)slot * N + gcol] = f2b(v);
        } else {
          int tok = token_of_slot[slot];
          if (tok >= 0)
            atomicAdd(&Out[(size_t)tok * N + gcol], v * weight_of_slot[slot]);
        }
      }
    }
  }
}

extern "C" void kernel_launch(void* const* d_in, const int* in_sizes, int n_in,
                              void* d_out, int out_size, void* d_ws, size_t ws_size,
                              hipStream_t stream) {
  const float* x  = (const float*)d_in[0];
  const float* Wr = (const float*)d_in[1];
  const float* br = (const float*)d_in[2];
  const float* W1 = (const float*)d_in[3];
  const float* b1 = (const float*)d_in[4];
  const float* W2 = (const float*)d_in[5];
  const float* b2 = (const float*)d_in[6];
  float* out = (float*)d_out;
  char* ws = (char*)d_ws;

  u16*   W1t  = (u16*)(ws + OFF_W1T);
  u16*   W2t  = (u16*)(ws + OFF_W2T);
  u16*   xb   = (u16*)(ws + OFF_XB);
  u16*   hbuf = (u16*)(ws + OFF_H);
  int*   tos  = (int*)(ws + OFF_TOS);
  float* wos  = (float*)(ws + OFF_WOS);
  int*   tki  = (int*)(ws + OFF_TKI);
  float* tkw  = (float*)(ws + OFF_TKW);
  int*   cnt  = (int*)(ws + OFF_CNT);
  int*   pof  = (int*)(ws + OFF_POF);
  int*   cur  = (int*)(ws + OFF_CUR);
  int*   nt   = (int*)(ws + OFF_NT);
  int*   te   = (int*)(ws + OFF_TE);
  int*   ts   = (int*)(ws + OFF_TS);

  hipMemsetAsync(out, 0, (size_t)N_TOK * DIM * sizeof(float), stream);
  hipMemsetAsync(tos, 0xFF, (size_t)MAX_SLOTS * sizeof(int), stream);  // -1
  hipMemsetAsync(cnt, 0, 8 * sizeof(int), stream);

  transpose_to_bf16<<<dim3(NE * (DIM / 32) * (HID / 32)), 256, 0, stream>>>(W1, W1t, DIM, HID);
  transpose_to_bf16<<<dim3(NE * (HID / 32) * (DIM / 32)), 256, 0, stream>>>(W2, W2t, HID, DIM);
  convert_x<<<dim3(N_TOK * DIM / (256 * 8)), 256, 0, stream>>>(x, xb);
  router_kernel<<<dim3(N_TOK / 4), 256, 0, stream>>>(x, Wr, br, tki, tkw, cnt);
  plan_kernel<<<dim3(1), 64, 0, stream>>>(cnt, pof, cur, nt, te, ts);
  scatter_kernel<<<dim3(N_TOK / 256), 256, 0, stream>>>(tki, tkw, pof, cur, tos, wos);

  moe_gemm<1><<<dim3(MAX_SLOTS / 128, HID / 128), 256, 0, stream>>>(
      xb, W1t, b1, hbuf, nullptr, te, ts, nt, tos, wos, DIM, HID);
  moe_gemm<2><<<dim3(MAX_SLOTS / 128, DIM / 128), 256, 0, stream>>>(
      hbuf, W2t, b2, nullptr, out, te, ts, nt, tos, wos, HID, DIM);
}

// Round 2
// 1179.599 us; speedup vs baseline: 1.0170x; 1.0170x over previous
//
#include <hip/hip_runtime.h>
#include <stdint.h>

typedef unsigned short u16;
typedef __attribute__((ext_vector_type(8))) short s8bf;   // 8 bf16 in 4 VGPRs
typedef __attribute__((ext_vector_type(4))) float f32x4;

#define N_TOK 8192
#define DIM   1024
#define HID   4096
#define NE    8
#define MAX_SLOTS 17408   // 16384 + 8*128 worst-case padding
#define MAX_TILES 160

// ---- workspace layout (bytes) ----
#define OFF_W1T  ((size_t)0)                    // [E][HID][DIM] bf16  (transposed, n-major)
#define OFF_W2T  ((size_t)67108864)             // [E][DIM][HID] bf16
#define OFF_XB   ((size_t)134217728)            // [N_TOK][DIM] bf16
#define OFF_H    ((size_t)150994944)            // [MAX_SLOTS][HID] bf16
#define OFF_TOS  ((size_t)293601280)            // token_of_slot int[MAX_SLOTS]
#define OFF_WOS  ((size_t)293670912)            // weight_of_slot float[MAX_SLOTS]
#define OFF_TKI  ((size_t)293740544)            // topk idx int[N_TOK*2]
#define OFF_TKW  ((size_t)293806080)            // topk w  float[N_TOK*2]
#define OFF_CNT  ((size_t)293871616)            // counts int[8]
#define OFF_POF  ((size_t)293871680)            // padded offsets int[8]
#define OFF_CUR  ((size_t)293871744)            // cursors int[8]
#define OFF_NT   ((size_t)293871808)            // n_tiles int[1]
#define OFF_TE   ((size_t)293871872)            // tile_expert int[MAX_TILES]
#define OFF_TS   ((size_t)293872896)            // tile_slot0  int[MAX_TILES]

__device__ __forceinline__ u16 f2b(float v) {   // fp32 -> bf16 RNE
  union { float f; uint32_t u; } c; c.f = v;
  uint32_t u = c.u;
  return (u16)((u + 0x7FFFu + ((u >> 16) & 1u)) >> 16);
}

// async global->LDS DMA, 16 B per lane. lds ptr must be wave-uniform;
// HW writes lane i at l + i*16.
typedef const __attribute__((address_space(1))) uint32_t* gp32;
typedef __attribute__((address_space(3))) uint32_t* lp32;
__device__ __forceinline__ void gl_lds16(const u16* g, u16* l) {
  __builtin_amdgcn_global_load_lds((gp32)(const void*)g, (lp32)(void*)l, 16, 0, 0);
}

// ---- fp32 [R][C] -> bf16 [C][R] transpose (per expert), 64x64 LDS tiles ----
__global__ __launch_bounds__(256) void transpose_to_bf16(
    const float* __restrict__ in, u16* __restrict__ out, int R, int C) {
  __shared__ float tile[64][65];
  int tiles_c = C >> 6, tiles_r = R >> 6;
  int per = tiles_c * tiles_r;
  int e = blockIdx.x / per, t = blockIdx.x % per;
  int tr = t / tiles_c, tc = t % tiles_c;
  const float* ip = in + (size_t)e * R * C + (size_t)(tr * 64) * C + tc * 64;
  u16* op = out + (size_t)e * R * C + (size_t)(tc * 64) * R + tr * 64;
  int tx = threadIdx.x & 63, ty = threadIdx.x >> 6;
  #pragma unroll
  for (int i = 0; i < 16; i++)
    tile[ty + i * 4][tx] = ip[(size_t)(ty + i * 4) * C + tx];
  __syncthreads();
  // out row oc (= input col) is 64 contiguous u16; pack 2 per lane (u32 stores)
  int c2 = threadIdx.x & 31, orow = threadIdx.x >> 5;
  #pragma unroll
  for (int i = 0; i < 8; i++) {
    int oc = orow + i * 8;
    uint32_t pk = (uint32_t)f2b(tile[2 * c2][oc]) |
                  ((uint32_t)f2b(tile[2 * c2 + 1][oc]) << 16);
    *(uint32_t*)(op + (size_t)oc * R + 2 * c2) = pk;
  }
}

// ---- x fp32 -> bf16 ----
__global__ __launch_bounds__(256) void convert_x(const float* __restrict__ x,
                                                 u16* __restrict__ xb) {
  size_t i = ((size_t)blockIdx.x * 256 + threadIdx.x) * 8;
  float4 v0 = *(const float4*)(x + i);
  float4 v1 = *(const float4*)(x + i + 4);
  u16 o[8] = {f2b(v0.x), f2b(v0.y), f2b(v0.z), f2b(v0.w),
              f2b(v1.x), f2b(v1.y), f2b(v1.z), f2b(v1.w)};
  *(uint4*)(xb + i) = *(const uint4*)o;
}

// ---- router: logits -> top2 -> renormalized weights (fp32). one wave/token ----
__global__ __launch_bounds__(256) void router_kernel(
    const float* __restrict__ x, const float* __restrict__ Wr,
    const float* __restrict__ br, int* __restrict__ tki, float* __restrict__ tkw,
    int* __restrict__ counts) {
  int wave = threadIdx.x >> 6, lane = threadIdx.x & 63;
  int t = blockIdx.x * 4 + wave;
  const float* xr = x + (size_t)t * DIM;
  float acc[8] = {0.f, 0.f, 0.f, 0.f, 0.f, 0.f, 0.f, 0.f};
  #pragma unroll
  for (int i = 0; i < 16; i++) {
    int d = lane + i * 64;
    float xv = xr[d];
    float4 wa = *(const float4*)(Wr + d * 8);
    float4 wb = *(const float4*)(Wr + d * 8 + 4);
    acc[0] += xv * wa.x; acc[1] += xv * wa.y; acc[2] += xv * wa.z; acc[3] += xv * wa.w;
    acc[4] += xv * wb.x; acc[5] += xv * wb.y; acc[6] += xv * wb.z; acc[7] += xv * wb.w;
  }
  #pragma unroll
  for (int e = 0; e < 8; e++)
    #pragma unroll
    for (int off = 32; off >= 1; off >>= 1)
      acc[e] += __shfl_xor(acc[e], off, 64);
  if (lane == 0) {
    float l[8];
    #pragma unroll
    for (int e = 0; e < 8; e++) l[e] = acc[e] + br[e];
    float l0 = -1e30f; int i0 = 0;
    #pragma unroll
    for (int e = 0; e < 8; e++) if (l[e] > l0) { l0 = l[e]; i0 = e; }
    float l1 = -1e30f; int i1 = 0;
    #pragma unroll
    for (int e = 0; e < 8; e++) if (e != i0 && l[e] > l1) { l1 = l[e]; i1 = e; }
    float w0 = 1.f / (1.f + expf(l1 - l0));
    tki[t * 2] = i0; tki[t * 2 + 1] = i1;
    tkw[t * 2] = w0; tkw[t * 2 + 1] = 1.f - w0;
    atomicAdd(&counts[i0], 1);
    atomicAdd(&counts[i1], 1);
  }
}

// ---- plan: padded per-expert offsets + tile list ----
__global__ void plan_kernel(const int* __restrict__ counts, int* __restrict__ poff,
                            int* __restrict__ cursor, int* __restrict__ ntiles,
                            int* __restrict__ tile_e, int* __restrict__ tile_s0) {
  if (threadIdx.x == 0 && blockIdx.x == 0) {
    int po = 0, nt = 0;
    for (int e = 0; e < NE; e++) {
      poff[e] = po;
      cursor[e] = 0;
      int c = counts[e];
      int tl = (c + 127) >> 7;
      for (int j = 0; j < tl; j++) { tile_e[nt] = e; tile_s0[nt] = po + j * 128; nt++; }
      po += tl << 7;
    }
    ntiles[0] = nt;
  }
}

// ---- scatter tokens into per-expert slots ----
__global__ __launch_bounds__(256) void scatter_kernel(
    const int* __restrict__ tki, const float* __restrict__ tkw,
    const int* __restrict__ poff, int* __restrict__ cursor,
    int* __restrict__ token_of_slot, float* __restrict__ weight_of_slot) {
  int t = blockIdx.x * 256 + threadIdx.x;
  #pragma unroll
  for (int k = 0; k < 2; k++) {
    int e = tki[t * 2 + k];
    int r = atomicAdd(&cursor[e], 1);
    int s = poff[e] + r;
    token_of_slot[s] = t;
    weight_of_slot[s] = tkw[t * 2 + k];
  }
}

// ---- grouped GEMM: C[128x128] per block, 4 waves, 16x16x32 bf16 MFMA ----
// Staging via global_load_lds width=16 (m97 structure).
// MODE 1: A = xb gathered by token_of_slot, epilogue relu(acc+b1) -> h (bf16)
// MODE 2: A = h by slot,                   epilogue (acc+b2)*w atomicAdd-> out
template <int MODE>
__global__ __launch_bounds__(256) void moe_gemm(
    const u16* __restrict__ A, const u16* __restrict__ Bt,
    const float* __restrict__ bias, u16* __restrict__ Hout,
    float* __restrict__ Out, const int* __restrict__ tile_e,
    const int* __restrict__ tile_s0, const int* __restrict__ ntiles,
    const int* __restrict__ token_of_slot, const float* __restrict__ weight_of_slot,
    int K, int N) {
  if ((int)blockIdx.x >= ntiles[0]) return;
  const int e = tile_e[blockIdx.x];
  const int slot0 = tile_s0[blockIdx.x];
  const int n0 = blockIdx.y * 128;

  __shared__ u16 lA[128 * 32];
  __shared__ u16 lB[128 * 32];

  const int tid = threadIdx.x;
  const int lane = tid & 63;
  const int wave = tid >> 6;
  const int wm = wave >> 1, wn = wave & 1;

  // staging map: chunk c (=tid, tid+256) -> row c>>2, cols (c&3)*8..+7,
  // LDS byte offset c*16 == wave_base + lane*16  (global_load_lds layout)
  const int r0 = tid >> 2, r1 = r0 + 64;
  const int c8 = (tid & 3) * 8;
  int arow0, arow1;
  if (MODE == 1) {
    int t0 = token_of_slot[slot0 + r0]; arow0 = t0 < 0 ? 0 : t0;
    int t1 = token_of_slot[slot0 + r1]; arow1 = t1 < 0 ? 0 : t1;
  } else {
    arow0 = slot0 + r0; arow1 = slot0 + r1;
  }
  const u16* aP0 = A + (size_t)arow0 * K + c8;
  const u16* aP1 = A + (size_t)arow1 * K + c8;
  const u16* bE = Bt + (size_t)e * N * K;
  const u16* bP0 = bE + (size_t)(n0 + r0) * K + c8;
  const u16* bP1 = bE + (size_t)(n0 + r1) * K + c8;

  f32x4 acc[4][4];
  #pragma unroll
  for (int i = 0; i < 4; i++)
    #pragma unroll
    for (int j = 0; j < 4; j++) acc[i][j] = (f32x4){0.f, 0.f, 0.f, 0.f};

  const int qk = (lane >> 4) * 8;
  const int am = (lane & 15);

  for (int kb = 0; kb < K; kb += 32) {
    // each wave DMAs 4x 1KiB (64 lanes x 16B) into its LDS stripe
    gl_lds16(aP0 + kb, lA + wave * 512);
    gl_lds16(aP1 + kb, lA + 2048 + wave * 512);
    gl_lds16(bP0 + kb, lB + wave * 512);
    gl_lds16(bP1 + kb, lB + 2048 + wave * 512);
    __syncthreads();   // drains vmcnt -> staged data visible
    s8bf af[4], bf[4];
    #pragma unroll
    for (int mt = 0; mt < 4; mt++)
      af[mt] = *(const s8bf*)&lA[(wm * 64 + mt * 16 + am) * 32 + qk];
    #pragma unroll
    for (int nt = 0; nt < 4; nt++)
      bf[nt] = *(const s8bf*)&lB[(wn * 64 + nt * 16 + am) * 32 + qk];
    #pragma unroll
    for (int mt = 0; mt < 4; mt++)
      #pragma unroll
      for (int nt = 0; nt < 4; nt++)
        acc[mt][nt] = __builtin_amdgcn_mfma_f32_16x16x32_bf16(af[mt], bf[nt],
                                                              acc[mt][nt], 0, 0, 0);
    __syncthreads();   // all reads done before next iter's DMA overwrites
  }

  // epilogue: C/D layout col=lane&15, row=(lane>>4)*4+reg
  const int colq = lane & 15;
  const int rq = (lane >> 4) * 4;
  #pragma unroll
  for (int nt = 0; nt < 4; nt++) {
    int gcol = n0 + wn * 64 + nt * 16 + colq;
    float bv = bias[(size_t)e * N + gcol];
    #pragma unroll
    for (int mt = 0; mt < 4; mt++) {
      int rowbase = wm * 64 + mt * 16 + rq;
      #pragma unroll
      for (int r = 0; r < 4; r++) {
        int slot = slot0 + rowbase + r;
        float v = acc[mt][nt][r] + bv;
        if (MODE == 1) {
          v = fmaxf(v, 0.f);
          Hout[(size_t)slot * N + gcol] = f2b(v);
        } else {
          int tok = token_of_slot[slot];
          if (tok >= 0)
            atomicAdd(&Out[(size_t)tok * N + gcol], v * weight_of_slot[slot]);
        }
      }
    }
  }
}

extern "C" void kernel_launch(void* const* d_in, const int* in_sizes, int n_in,
                              void* d_out, int out_size, void* d_ws, size_t ws_size,
                              hipStream_t stream) {
  const float* x  = (const float*)d_in[0];
  const float* Wr = (const float*)d_in[1];
  const float* br = (const float*)d_in[2];
  const float* W1 = (const float*)d_in[3];
  const float* b1 = (const float*)d_in[4];
  const float* W2 = (const float*)d_in[5];
  const float* b2 = (const float*)d_in[6];
  float* out = (float*)d_out;
  char* ws = (char*)d_ws;

  u16*   W1t  = (u16*)(ws + OFF_W1T);
  u16*   W2t  = (u16*)(ws + OFF_W2T);
  u16*   xb   = (u16*)(ws + OFF_XB);
  u16*   hbuf = (u16*)(ws + OFF_H);
  int*   tos  = (int*)(ws + OFF_TOS);
  float* wos  = (float*)(ws + OFF_WOS);
  int*   tki  = (int*)(ws + OFF_TKI);
  float* tkw  = (float*)(ws + OFF_TKW);
  int*   cnt  = (int*)(ws + OFF_CNT);
  int*   pof  = (int*)(ws + OFF_POF);
  int*   cur  = (int*)(ws + OFF_CUR);
  int*   nt   = (int*)(ws + OFF_NT);
  int*   te   = (int*)(ws + OFF_TE);
  int*   ts   = (int*)(ws + OFF_TS);

  hipMemsetAsync(out, 0, (size_t)N_TOK * DIM * sizeof(float), stream);
  hipMemsetAsync(tos, 0xFF, (size_t)MAX_SLOTS * sizeof(int), stream);  // -1
  hipMemsetAsync(cnt, 0, 8 * sizeof(int), stream);

  transpose_to_bf16<<<dim3(NE * (DIM / 64) * (HID / 64)), 256, 0, stream>>>(W1, W1t, DIM, HID);
  transpose_to_bf16<<<dim3(NE * (HID / 64) * (DIM / 64)), 256, 0, stream>>>(W2, W2t, HID, DIM);
  convert_x<<<dim3(N_TOK * DIM / (256 * 8)), 256, 0, stream>>>(x, xb);
  router_kernel<<<dim3(N_TOK / 4), 256, 0, stream>>>(x, Wr, br, tki, tkw, cnt);
  plan_kernel<<<dim3(1), 64, 0, stream>>>(cnt, pof, cur, nt, te, ts);
  scatter_kernel<<<dim3(N_TOK / 256), 256, 0, stream>>>(tki, tkw, pof, cur, tos, wos);

  moe_gemm<1><<<dim3(MAX_SLOTS / 128, HID / 128), 256, 0, stream>>>(
      xb, W1t, b1, hbuf, nullptr, te, ts, nt, tos, wos, DIM, HID);
  moe_gemm<2><<<dim3(MAX_SLOTS / 128, DIM / 128), 256, 0, stream>>>(
      hbuf, W2t, b2, nullptr, out, te, ts, nt, tos, wos, HID, DIM);
}

// Round 3
// 1139.376 us; speedup vs baseline: 1.0529x; 1.0353x over previous
//
#include <hip/hip_runtime.h>
#include <stdint.h>

typedef unsigned short u16;
typedef __attribute__((ext_vector_type(8))) short s8bf;   // 8 bf16 in 4 VGPRs
typedef __attribute__((ext_vector_type(4))) float f32x4;

#define N_TOK 8192
#define DIM   1024
#define HID   4096
#define NE    8
#define MAX_SLOTS 17408   // 16384 + 8*128 worst-case padding
#define MAX_TILES 160

// ---- workspace layout (bytes) ----
#define OFF_W1T  ((size_t)0)                    // [E][HID][DIM] bf16  (n-major, k-contig)
#define OFF_W2T  ((size_t)67108864)             // [E][DIM][HID] bf16
#define OFF_XB   ((size_t)134217728)            // [N_TOK][DIM] bf16
#define OFF_H    ((size_t)150994944)            // [MAX_SLOTS][HID] bf16
#define OFF_TOS  ((size_t)293601280)            // token_of_slot int[MAX_SLOTS]
#define OFF_WOS  ((size_t)293670912)            // weight_of_slot float[MAX_SLOTS]
#define OFF_TKI  ((size_t)293740544)            // topk idx int[N_TOK*2]
#define OFF_TKW  ((size_t)293806080)            // topk w  float[N_TOK*2]
#define OFF_CNT  ((size_t)293871616)            // counts int[8]
#define OFF_POF  ((size_t)293871680)            // padded offsets int[8]
#define OFF_CUR  ((size_t)293871744)            // cursors int[8]
#define OFF_NT   ((size_t)293871808)            // n_tiles int[1]
#define OFF_TE   ((size_t)293871872)            // tile_expert int[MAX_TILES]
#define OFF_TS   ((size_t)293872896)            // tile_slot0  int[MAX_TILES]

__device__ __forceinline__ u16 f2b(float v) {   // fp32 -> bf16 RNE
  union { float f; uint32_t u; } c; c.f = v;
  uint32_t u = c.u;
  return (u16)((u + 0x7FFFu + ((u >> 16) & 1u)) >> 16);
}

// async global->LDS DMA, 16 B per lane. lds ptr wave-uniform; lane i -> l + i*16.
typedef const __attribute__((address_space(1))) uint32_t* gp32;
typedef __attribute__((address_space(3))) uint32_t* lp32;
__device__ __forceinline__ void gl_lds16(const u16* g, u16* l) {
  __builtin_amdgcn_global_load_lds((gp32)(const void*)g, (lp32)(void*)l, 16, 0, 0);
}

// ---- fused fp32 [R][C] -> bf16 [C][R] transpose, 256(R) x 64(C) tiles ----
// reads 256B-coalesced, writes 512B-contiguous uint4 runs.
__global__ __launch_bounds__(256) void transpose_to_bf16(
    const float* __restrict__ in, u16* __restrict__ out, int R, int C) {
  __shared__ u16 L[64][264];   // [c][r], +8 pad
  int tiles_c = C >> 6, tiles_r = R >> 8;
  int per = tiles_c * tiles_r;
  int e = blockIdx.x / per, t = blockIdx.x % per;
  int tr = t / tiles_c, tc = t % tiles_c;
  const float* ip = in + (size_t)e * R * C + (size_t)(tr * 256) * C + tc * 64;
  u16* op = out + (size_t)e * R * C + (size_t)(tc * 64) * R + tr * 256;
  const int tid = threadIdx.x;
  // phase 1: load fp32, convert, write transposed into LDS
  const int c4 = (tid & 15) * 4;
  #pragma unroll
  for (int p = 0; p < 16; p++) {
    int r = p * 16 + (tid >> 4);
    float4 v = *(const float4*)(ip + (size_t)r * C + c4);
    L[c4 + 0][r] = f2b(v.x);
    L[c4 + 1][r] = f2b(v.y);
    L[c4 + 2][r] = f2b(v.z);
    L[c4 + 3][r] = f2b(v.w);
  }
  __syncthreads();
  // phase 2: write out rows (each 256 u16 = 512 B contiguous)
  const int s = tid & 31;
  #pragma unroll
  for (int p = 0; p < 8; p++) {
    int oc = p * 8 + (tid >> 5);
    u16 tmp[8];
    #pragma unroll
    for (int j = 0; j < 8; j++) tmp[j] = L[oc][s * 8 + j];
    *(uint4*)(op + (size_t)oc * R + s * 8) = *(const uint4*)tmp;
  }
}

// ---- x fp32 -> bf16 ----
__global__ __launch_bounds__(256) void convert_x(const float* __restrict__ x,
                                                 u16* __restrict__ xb) {
  size_t i = ((size_t)blockIdx.x * 256 + threadIdx.x) * 8;
  float4 v0 = *(const float4*)(x + i);
  float4 v1 = *(const float4*)(x + i + 4);
  u16 o[8] = {f2b(v0.x), f2b(v0.y), f2b(v0.z), f2b(v0.w),
              f2b(v1.x), f2b(v1.y), f2b(v1.z), f2b(v1.w)};
  *(uint4*)(xb + i) = *(const uint4*)o;
}

// ---- router: logits -> top2 -> renormalized weights (fp32). one wave/token ----
__global__ __launch_bounds__(256) void router_kernel(
    const float* __restrict__ x, const float* __restrict__ Wr,
    const float* __restrict__ br, int* __restrict__ tki, float* __restrict__ tkw,
    int* __restrict__ counts) {
  int wave = threadIdx.x >> 6, lane = threadIdx.x & 63;
  int t = blockIdx.x * 4 + wave;
  const float* xr = x + (size_t)t * DIM;
  float acc[8] = {0.f, 0.f, 0.f, 0.f, 0.f, 0.f, 0.f, 0.f};
  #pragma unroll
  for (int i = 0; i < 16; i++) {
    int d = lane + i * 64;
    float xv = xr[d];
    float4 wa = *(const float4*)(Wr + d * 8);
    float4 wb = *(const float4*)(Wr + d * 8 + 4);
    acc[0] += xv * wa.x; acc[1] += xv * wa.y; acc[2] += xv * wa.z; acc[3] += xv * wa.w;
    acc[4] += xv * wb.x; acc[5] += xv * wb.y; acc[6] += xv * wb.z; acc[7] += xv * wb.w;
  }
  #pragma unroll
  for (int e = 0; e < 8; e++)
    #pragma unroll
    for (int off = 32; off >= 1; off >>= 1)
      acc[e] += __shfl_xor(acc[e], off, 64);
  if (lane == 0) {
    float l[8];
    #pragma unroll
    for (int e = 0; e < 8; e++) l[e] = acc[e] + br[e];
    float l0 = -1e30f; int i0 = 0;
    #pragma unroll
    for (int e = 0; e < 8; e++) if (l[e] > l0) { l0 = l[e]; i0 = e; }
    float l1 = -1e30f; int i1 = 0;
    #pragma unroll
    for (int e = 0; e < 8; e++) if (e != i0 && l[e] > l1) { l1 = l[e]; i1 = e; }
    float w0 = 1.f / (1.f + expf(l1 - l0));
    tki[t * 2] = i0; tki[t * 2 + 1] = i1;
    tkw[t * 2] = w0; tkw[t * 2 + 1] = 1.f - w0;
    atomicAdd(&counts[i0], 1);
    atomicAdd(&counts[i1], 1);
  }
}

// ---- plan: padded per-expert offsets + tile list ----
__global__ void plan_kernel(const int* __restrict__ counts, int* __restrict__ poff,
                            int* __restrict__ cursor, int* __restrict__ ntiles,
                            int* __restrict__ tile_e, int* __restrict__ tile_s0) {
  if (threadIdx.x == 0 && blockIdx.x == 0) {
    int po = 0, nt = 0;
    for (int e = 0; e < NE; e++) {
      poff[e] = po;
      cursor[e] = 0;
      int c = counts[e];
      int tl = (c + 127) >> 7;
      for (int j = 0; j < tl; j++) { tile_e[nt] = e; tile_s0[nt] = po + j * 128; nt++; }
      po += tl << 7;
    }
    ntiles[0] = nt;
  }
}

// ---- scatter tokens into per-expert slots ----
__global__ __launch_bounds__(256) void scatter_kernel(
    const int* __restrict__ tki, const float* __restrict__ tkw,
    const int* __restrict__ poff, int* __restrict__ cursor,
    int* __restrict__ token_of_slot, float* __restrict__ weight_of_slot) {
  int t = blockIdx.x * 256 + threadIdx.x;
  #pragma unroll
  for (int k = 0; k < 2; k++) {
    int e = tki[t * 2 + k];
    int r = atomicAdd(&cursor[e], 1);
    int s = poff[e] + r;
    token_of_slot[s] = t;
    weight_of_slot[s] = tkw[t * 2 + k];
  }
}

// ---- grouped GEMM: C[128x128]/block, 4 waves, 16x16x32 bf16 MFMA, BK=64 ----
// 1D grid, nblk = bid % NB (fast) -> XCD-stationary B stripes (bid%8 = XCD).
// BK=64 as two conflict-optimal BK=32 panels sharing one barrier pair.
// MODE 1: A = xb gathered by token_of_slot, epilogue relu(acc+b1) -> h (bf16)
// MODE 2: A = h by slot,                   epilogue (acc+b2)*w atomicAdd-> out
template <int MODE>
__global__ __launch_bounds__(256) void moe_gemm(
    const u16* __restrict__ A, const u16* __restrict__ Bt,
    const float* __restrict__ bias, u16* __restrict__ Hout,
    float* __restrict__ Out, const int* __restrict__ tile_e,
    const int* __restrict__ tile_s0, const int* __restrict__ ntiles,
    const int* __restrict__ token_of_slot, const float* __restrict__ weight_of_slot,
    int K, int N, int NB) {
  const int nblk = blockIdx.x % NB;
  const int tileid = blockIdx.x / NB;
  if (tileid >= ntiles[0]) return;
  const int e = tile_e[tileid];
  const int slot0 = tile_s0[tileid];
  const int n0 = nblk * 128;

  __shared__ u16 lA[2][128 * 32];
  __shared__ u16 lB[2][128 * 32];

  const int tid = threadIdx.x;
  const int lane = tid & 63;
  const int wave = tid >> 6;
  const int wm = wave >> 1, wn = wave & 1;

  // staging map (per panel): chunk c (=tid, tid+256) -> row c>>2, cols (c&3)*8..+7,
  // LDS byte offset c*16 == wave_base + lane*16  (global_load_lds layout)
  const int r0 = tid >> 2, r1 = r0 + 64;
  const int c8 = (tid & 3) * 8;
  int arow0, arow1;
  if (MODE == 1) {
    int t0 = token_of_slot[slot0 + r0]; arow0 = t0 < 0 ? 0 : t0;
    int t1 = token_of_slot[slot0 + r1]; arow1 = t1 < 0 ? 0 : t1;
  } else {
    arow0 = slot0 + r0; arow1 = slot0 + r1;
  }
  const u16* aP0 = A + (size_t)arow0 * K + c8;
  const u16* aP1 = A + (size_t)arow1 * K + c8;
  const u16* bE = Bt + (size_t)e * N * K;
  const u16* bP0 = bE + (size_t)(n0 + r0) * K + c8;
  const u16* bP1 = bE + (size_t)(n0 + r1) * K + c8;

  f32x4 acc[4][4];
  #pragma unroll
  for (int i = 0; i < 4; i++)
    #pragma unroll
    for (int j = 0; j < 4; j++) acc[i][j] = (f32x4){0.f, 0.f, 0.f, 0.f};

  const int qk = (lane >> 4) * 8;
  const int am = (lane & 15);

  for (int kb = 0; kb < K; kb += 64) {
    #pragma unroll
    for (int h = 0; h < 2; h++) {
      int ko = kb + h * 32;
      gl_lds16(aP0 + ko, lA[h] + wave * 512);
      gl_lds16(aP1 + ko, lA[h] + 2048 + wave * 512);
      gl_lds16(bP0 + ko, lB[h] + wave * 512);
      gl_lds16(bP1 + ko, lB[h] + 2048 + wave * 512);
    }
    __syncthreads();   // drains vmcnt -> staged data visible
    #pragma unroll
    for (int h = 0; h < 2; h++) {
      s8bf af[4], bf[4];
      #pragma unroll
      for (int mt = 0; mt < 4; mt++)
        af[mt] = *(const s8bf*)&lA[h][(wm * 64 + mt * 16 + am) * 32 + qk];
      #pragma unroll
      for (int nt = 0; nt < 4; nt++)
        bf[nt] = *(const s8bf*)&lB[h][(wn * 64 + nt * 16 + am) * 32 + qk];
      #pragma unroll
      for (int mt = 0; mt < 4; mt++)
        #pragma unroll
        for (int nt = 0; nt < 4; nt++)
          acc[mt][nt] = __builtin_amdgcn_mfma_f32_16x16x32_bf16(af[mt], bf[nt],
                                                                acc[mt][nt], 0, 0, 0);
    }
    __syncthreads();   // all reads done before next iter's DMA overwrites
  }

  // epilogue: C/D layout col=lane&15, row=(lane>>4)*4+reg
  const int colq = lane & 15;
  const int rq = (lane >> 4) * 4;
  #pragma unroll
  for (int nt = 0; nt < 4; nt++) {
    int gcol = n0 + wn * 64 + nt * 16 + colq;
    float bv = bias[(size_t)e * N + gcol];
    #pragma unroll
    for (int mt = 0; mt < 4; mt++) {
      int rowbase = wm * 64 + mt * 16 + rq;
      #pragma unroll
      for (int r = 0; r < 4; r++) {
        int slot = slot0 + rowbase + r;
        float v = acc[mt][nt][r] + bv;
        if (MODE == 1) {
          v = fmaxf(v, 0.f);
          Hout[(size_t)slot * N + gcol] = f2b(v);
        } else {
          int tok = token_of_slot[slot];
          if (tok >= 0)
            atomicAdd(&Out[(size_t)tok * N + gcol], v * weight_of_slot[slot]);
        }
      }
    }
  }
}

extern "C" void kernel_launch(void* const* d_in, const int* in_sizes, int n_in,
                              void* d_out, int out_size, void* d_ws, size_t ws_size,
                              hipStream_t stream) {
  const float* x  = (const float*)d_in[0];
  const float* Wr = (const float*)d_in[1];
  const float* br = (const float*)d_in[2];
  const float* W1 = (const float*)d_in[3];
  const float* b1 = (const float*)d_in[4];
  const float* W2 = (const float*)d_in[5];
  const float* b2 = (const float*)d_in[6];
  float* out = (float*)d_out;
  char* ws = (char*)d_ws;

  u16*   W1t  = (u16*)(ws + OFF_W1T);
  u16*   W2t  = (u16*)(ws + OFF_W2T);
  u16*   xb   = (u16*)(ws + OFF_XB);
  u16*   hbuf = (u16*)(ws + OFF_H);
  int*   tos  = (int*)(ws + OFF_TOS);
  float* wos  = (float*)(ws + OFF_WOS);
  int*   tki  = (int*)(ws + OFF_TKI);
  float* tkw  = (float*)(ws + OFF_TKW);
  int*   cnt  = (int*)(ws + OFF_CNT);
  int*   pof  = (int*)(ws + OFF_POF);
  int*   cur  = (int*)(ws + OFF_CUR);
  int*   nt   = (int*)(ws + OFF_NT);
  int*   te   = (int*)(ws + OFF_TE);
  int*   ts   = (int*)(ws + OFF_TS);

  hipMemsetAsync(out, 0, (size_t)N_TOK * DIM * sizeof(float), stream);
  hipMemsetAsync(tos, 0xFF, (size_t)MAX_SLOTS * sizeof(int), stream);  // -1
  hipMemsetAsync(cnt, 0, 8 * sizeof(int), stream);

  // tiles: NE * (R/256) * (C/64)
  transpose_to_bf16<<<dim3(NE * (DIM / 256) * (HID / 64)), 256, 0, stream>>>(W1, W1t, DIM, HID);
  transpose_to_bf16<<<dim3(NE * (HID / 256) * (DIM / 64)), 256, 0, stream>>>(W2, W2t, HID, DIM);
  convert_x<<<dim3(N_TOK * DIM / (256 * 8)), 256, 0, stream>>>(x, xb);
  router_kernel<<<dim3(N_TOK / 4), 256, 0, stream>>>(x, Wr, br, tki, tkw, cnt);
  plan_kernel<<<dim3(1), 64, 0, stream>>>(cnt, pof, cur, nt, te, ts);
  scatter_kernel<<<dim3(N_TOK / 256), 256, 0, stream>>>(tki, tkw, pof, cur, tos, wos);

  // 1D grid, n-block fastest -> XCD-stationary B
  moe_gemm<1><<<dim3((MAX_SLOTS / 128) * (HID / 128)), 256, 0, stream>>>(
      xb, W1t, b1, hbuf, nullptr, te, ts, nt, tos, wos, DIM, HID, HID / 128);
  moe_gemm<2><<<dim3((MAX_SLOTS / 128) * (DIM / 128)), 256, 0, stream>>>(
      hbuf, W2t, b2, nullptr, out, te, ts, nt, tos, wos, HID, DIM, DIM / 128);
}

// Round 4
// 1004.434 us; speedup vs baseline: 1.1944x; 1.1343x over previous
//
#include <hip/hip_runtime.h>
#include <stdint.h>

typedef unsigned short u16;
typedef __attribute__((ext_vector_type(8))) short s8bf;   // 8 bf16 in 4 VGPRs
typedef __attribute__((ext_vector_type(4))) float f32x4;

#define N_TOK 8192
#define DIM   1024
#define HID   4096
#define NE    8
#define MAX_SLOTS 17408   // 16384 + 8*128 worst-case padding
#define MAX_TILES 160
#define LSTR  152         // GEMM epilogue LDS row stride (u16): 304B, 16B-aligned, quad banks {0,16}
#define TSTR  264         // transpose LDS row stride (u16): 528B, 16B-aligned

// ---- workspace layout (bytes) ----
#define OFF_W1T  ((size_t)0)                    // [E][HID][DIM] bf16  (n-major, k-contig)
#define OFF_Y    ((size_t)0)                    // y bf16 [MAX_SLOTS][DIM] — overlays dead W1T
#define OFF_W2T  ((size_t)67108864)             // [E][DIM][HID] bf16
#define OFF_XB   ((size_t)134217728)            // [N_TOK][DIM] bf16
#define OFF_H    ((size_t)150994944)            // [MAX_SLOTS][HID] bf16
#define OFF_TOS  ((size_t)293601280)            // token_of_slot int[MAX_SLOTS]
#define OFF_SOT  ((size_t)293670912)            // slot_of_token int[N_TOK*2]
#define OFF_TKI  ((size_t)293740544)            // topk idx int[N_TOK*2]
#define OFF_TKW  ((size_t)293806080)            // topk w  float[N_TOK*2]
#define OFF_CNT  ((size_t)293871616)            // counts int[8]
#define OFF_POF  ((size_t)293871680)            // padded offsets int[8]
#define OFF_CUR  ((size_t)293871744)            // cursors int[8]
#define OFF_NT   ((size_t)293871808)            // n_tiles int[1]
#define OFF_TE   ((size_t)293871872)            // tile_expert int[MAX_TILES]
#define OFF_TS   ((size_t)293872896)            // tile_slot0  int[MAX_TILES]

__device__ __forceinline__ u16 f2b(float v) {   // fp32 -> bf16 RNE
  union { float f; uint32_t u; } c; c.f = v;
  uint32_t u = c.u;
  return (u16)((u + 0x7FFFu + ((u >> 16) & 1u)) >> 16);
}
__device__ __forceinline__ float b2f(u16 b) {
  union { uint32_t u; float f; } c; c.u = ((uint32_t)b) << 16; return c.f;
}

// async global->LDS DMA, 16 B per lane. lds ptr wave-uniform; lane i -> l + i*16.
typedef const __attribute__((address_space(1))) uint32_t* gp32;
typedef __attribute__((address_space(3))) uint32_t* lp32;
__device__ __forceinline__ void gl_lds16(const u16* g, u16* l) {
  __builtin_amdgcn_global_load_lds((gp32)(const void*)g, (lp32)(void*)l, 16, 0, 0);
}

// ---- fused fp32 [R][C] -> bf16 [C][R] transpose, 256(R) x 64(C) tiles ----
// phase1: coalesced dword loads + ds_write_b128; phase2: ds_read_b128 + b128 stores.
__global__ __launch_bounds__(256) void transpose_to_bf16(
    const float* __restrict__ in, u16* __restrict__ out, int R, int C) {
  __shared__ u16 L[64 * TSTR];   // 33792 B
  int tiles_c = C >> 6, tiles_r = R >> 8;
  int per = tiles_c * tiles_r;
  int e = blockIdx.x / per, t = blockIdx.x % per;
  int tr = t / tiles_c, tc = t % tiles_c;
  const float* ip = in + (size_t)e * R * C + (size_t)(tr * 256) * C + tc * 64;
  u16* op = out + (size_t)e * R * C + (size_t)(tc * 64) * R + tr * 256;
  const int tid = threadIdx.x;
  const int c = tid & 63;
  const int rb0 = (tid >> 6) * 8;
  #pragma unroll
  for (int p = 0; p < 8; p++) {
    int rb = p * 32 + rb0;
    u16 tmp[8];
    #pragma unroll
    for (int j = 0; j < 8; j++) tmp[j] = f2b(ip[(size_t)(rb + j) * C + c]);
    *(uint4*)&L[c * TSTR + rb] = *(const uint4*)tmp;
  }
  __syncthreads();
  const int s = tid & 31, ocb = tid >> 5;
  #pragma unroll
  for (int p = 0; p < 8; p++) {
    int oc = p * 8 + ocb;
    uint4 v = *(const uint4*)&L[oc * TSTR + s * 8];
    *(uint4*)&op[(size_t)oc * R + s * 8] = v;
  }
}

// ---- x fp32 -> bf16 ----
__global__ __launch_bounds__(256) void convert_x(const float* __restrict__ x,
                                                 u16* __restrict__ xb) {
  size_t i = ((size_t)blockIdx.x * 256 + threadIdx.x) * 8;
  float4 v0 = *(const float4*)(x + i);
  float4 v1 = *(const float4*)(x + i + 4);
  u16 o[8] = {f2b(v0.x), f2b(v0.y), f2b(v0.z), f2b(v0.w),
              f2b(v1.x), f2b(v1.y), f2b(v1.z), f2b(v1.w)};
  *(uint4*)(xb + i) = *(const uint4*)o;
}

// ---- router: logits -> top2 -> renormalized weights (fp32). one wave/token ----
__global__ __launch_bounds__(256) void router_kernel(
    const float* __restrict__ x, const float* __restrict__ Wr,
    const float* __restrict__ br, int* __restrict__ tki, float* __restrict__ tkw,
    int* __restrict__ counts) {
  int wave = threadIdx.x >> 6, lane = threadIdx.x & 63;
  int t = blockIdx.x * 4 + wave;
  const float* xr = x + (size_t)t * DIM;
  float acc[8] = {0.f, 0.f, 0.f, 0.f, 0.f, 0.f, 0.f, 0.f};
  #pragma unroll
  for (int i = 0; i < 16; i++) {
    int d = lane + i * 64;
    float xv = xr[d];
    float4 wa = *(const float4*)(Wr + d * 8);
    float4 wb = *(const float4*)(Wr + d * 8 + 4);
    acc[0] += xv * wa.x; acc[1] += xv * wa.y; acc[2] += xv * wa.z; acc[3] += xv * wa.w;
    acc[4] += xv * wb.x; acc[5] += xv * wb.y; acc[6] += xv * wb.z; acc[7] += xv * wb.w;
  }
  #pragma unroll
  for (int e = 0; e < 8; e++)
    #pragma unroll
    for (int off = 32; off >= 1; off >>= 1)
      acc[e] += __shfl_xor(acc[e], off, 64);
  if (lane == 0) {
    float l[8];
    #pragma unroll
    for (int e = 0; e < 8; e++) l[e] = acc[e] + br[e];
    float l0 = -1e30f; int i0 = 0;
    #pragma unroll
    for (int e = 0; e < 8; e++) if (l[e] > l0) { l0 = l[e]; i0 = e; }
    float l1 = -1e30f; int i1 = 0;
    #pragma unroll
    for (int e = 0; e < 8; e++) if (e != i0 && l[e] > l1) { l1 = l[e]; i1 = e; }
    float w0 = 1.f / (1.f + expf(l1 - l0));
    tki[t * 2] = i0; tki[t * 2 + 1] = i1;
    tkw[t * 2] = w0; tkw[t * 2 + 1] = 1.f - w0;
    atomicAdd(&counts[i0], 1);
    atomicAdd(&counts[i1], 1);
  }
}

// ---- plan: padded per-expert offsets + tile list (parallel over experts) ----
__global__ void plan_kernel(const int* __restrict__ counts, int* __restrict__ poff,
                            int* __restrict__ cursor, int* __restrict__ ntiles,
                            int* __restrict__ tile_e, int* __restrict__ tile_s0) {
  int e = threadIdx.x;
  if (e < NE) {
    int po = 0, tb = 0;
    for (int i = 0; i < e; i++) {
      int tl = (counts[i] + 127) >> 7;
      po += tl << 7; tb += tl;
    }
    poff[e] = po;
    cursor[e] = 0;
    int tl = (counts[e] + 127) >> 7;
    for (int j = 0; j < tl; j++) { tile_e[tb + j] = e; tile_s0[tb + j] = po + j * 128; }
    if (e == NE - 1) ntiles[0] = tb + tl;
  }
}

// ---- scatter tokens into per-expert slots ----
__global__ __launch_bounds__(256) void scatter_kernel(
    const int* __restrict__ tki, const int* __restrict__ poff,
    int* __restrict__ cursor, int* __restrict__ token_of_slot,
    int* __restrict__ slot_of_token) {
  int t = blockIdx.x * 256 + threadIdx.x;
  #pragma unroll
  for (int k = 0; k < 2; k++) {
    int e = tki[t * 2 + k];
    int r = atomicAdd(&cursor[e], 1);
    int s = poff[e] + r;
    token_of_slot[s] = t;
    slot_of_token[t * 2 + k] = s;
  }
}

// ---- grouped GEMM: C[128x128]/block, 4 waves, 16x16x32 bf16 MFMA, BK=64 ----
// 1D grid, nblk = bid % NB (fast) -> XCD-stationary B stripes.
// Epilogue: acc -> bf16 via LDS roundtrip -> coalesced b128 stores.
// MODE 1: A rows gathered via token_of_slot, relu(acc+b1) -> h
// MODE 2: A rows = slots (h),               (acc+b2)      -> y
template <int MODE>
__global__ __launch_bounds__(256) void moe_gemm(
    const u16* __restrict__ A, const u16* __restrict__ Bt,
    const float* __restrict__ bias, u16* __restrict__ Hout,
    const int* __restrict__ tile_e, const int* __restrict__ tile_s0,
    const int* __restrict__ ntiles, const int* __restrict__ token_of_slot,
    int K, int N, int NB) {
  const int nblk = blockIdx.x % NB;
  const int tileid = blockIdx.x / NB;
  if (tileid >= ntiles[0]) return;
  const int e = tile_e[tileid];
  const int slot0 = tile_s0[tileid];
  const int n0 = nblk * 128;

  __shared__ u16 SM[128 * LSTR];   // 38912 B; staging uses first 32 KB
  u16* lA[2] = {SM, SM + 4096};
  u16* lB[2] = {SM + 8192, SM + 12288};

  const int tid = threadIdx.x;
  const int lane = tid & 63;
  const int wave = tid >> 6;
  const int wm = wave >> 1, wn = wave & 1;

  // staging map (per panel): chunk c (=tid, tid+256) -> row c>>2, cols (c&3)*8..+7,
  // LDS byte offset c*16 == wave_base + lane*16  (global_load_lds layout)
  const int r0 = tid >> 2, r1 = r0 + 64;
  const int c8 = (tid & 3) * 8;
  int arow0, arow1;
  if (MODE == 1) {
    int t0 = token_of_slot[slot0 + r0]; arow0 = t0 < 0 ? 0 : t0;
    int t1 = token_of_slot[slot0 + r1]; arow1 = t1 < 0 ? 0 : t1;
  } else {
    arow0 = slot0 + r0; arow1 = slot0 + r1;
  }
  const u16* aP0 = A + (size_t)arow0 * K + c8;
  const u16* aP1 = A + (size_t)arow1 * K + c8;
  const u16* bE = Bt + (size_t)e * N * K;
  const u16* bP0 = bE + (size_t)(n0 + r0) * K + c8;
  const u16* bP1 = bE + (size_t)(n0 + r1) * K + c8;

  f32x4 acc[4][4];
  #pragma unroll
  for (int i = 0; i < 4; i++)
    #pragma unroll
    for (int j = 0; j < 4; j++) acc[i][j] = (f32x4){0.f, 0.f, 0.f, 0.f};

  const int qk = (lane >> 4) * 8;
  const int am = (lane & 15);

  for (int kb = 0; kb < K; kb += 64) {
    #pragma unroll
    for (int h = 0; h < 2; h++) {
      int ko = kb + h * 32;
      gl_lds16(aP0 + ko, lA[h] + wave * 512);
      gl_lds16(aP1 + ko, lA[h] + 2048 + wave * 512);
      gl_lds16(bP0 + ko, lB[h] + wave * 512);
      gl_lds16(bP1 + ko, lB[h] + 2048 + wave * 512);
    }
    __syncthreads();   // drains vmcnt -> staged data visible
    #pragma unroll
    for (int h = 0; h < 2; h++) {
      s8bf af[4], bf[4];
      #pragma unroll
      for (int mt = 0; mt < 4; mt++)
        af[mt] = *(const s8bf*)&lA[h][(wm * 64 + mt * 16 + am) * 32 + qk];
      #pragma unroll
      for (int nt = 0; nt < 4; nt++)
        bf[nt] = *(const s8bf*)&lB[h][(wn * 64 + nt * 16 + am) * 32 + qk];
      #pragma unroll
      for (int mt = 0; mt < 4; mt++)
        #pragma unroll
        for (int nt = 0; nt < 4; nt++)
          acc[mt][nt] = __builtin_amdgcn_mfma_f32_16x16x32_bf16(af[mt], bf[nt],
                                                                acc[mt][nt], 0, 0, 0);
    }
    __syncthreads();   // all reads done before next iter's DMA overwrites
  }

  // epilogue: C/D layout col=lane&15, row=(lane>>4)*4+reg. Stage tile in LDS,
  // then stream out 256B-coalesced b128 rows.
  const int colq = lane & 15;
  const int rq = (lane >> 4) * 4;
  #pragma unroll
  for (int nt = 0; nt < 4; nt++) {
    int lcol = wn * 64 + nt * 16 + colq;
    float bv = bias[(size_t)e * N + n0 + lcol];
    #pragma unroll
    for (int mt = 0; mt < 4; mt++) {
      int rowbase = wm * 64 + mt * 16 + rq;
      #pragma unroll
      for (int r = 0; r < 4; r++) {
        float v = acc[mt][nt][r] + bv;
        if (MODE == 1) v = fmaxf(v, 0.f);
        SM[(rowbase + r) * LSTR + lcol] = f2b(v);
      }
    }
  }
  __syncthreads();
  #pragma unroll
  for (int k = 0; k < 8; k++) {
    int ch = k * 256 + tid;
    int row = ch >> 4;
    int cp = (ch & 15) * 8;
    uint4 v = *(const uint4*)&SM[row * LSTR + cp];
    *(uint4*)&Hout[(size_t)(slot0 + row) * N + n0 + cp] = v;
  }
}

// ---- combine: out[t] = w0*y[s0] + w1*y[s1] (y bf16, out fp32) ----
__global__ __launch_bounds__(256) void combine_kernel(
    const u16* __restrict__ y, const int* __restrict__ sot,
    const float* __restrict__ tkw, float* __restrict__ out) {
  int wave = threadIdx.x >> 6, lane = threadIdx.x & 63;
  int t = blockIdx.x * 4 + wave;
  int s0 = sot[t * 2], s1 = sot[t * 2 + 1];
  float w0 = tkw[t * 2], w1 = tkw[t * 2 + 1];
  const u16* y0 = y + (size_t)s0 * DIM;
  const u16* y1 = y + (size_t)s1 * DIM;
  float* op = out + (size_t)t * DIM;
  #pragma unroll
  for (int i = 0; i < 4; i++) {
    int d = i * 256 + lane * 4;
    uint2 a = *(const uint2*)(y0 + d);
    uint2 b = *(const uint2*)(y1 + d);
    float4 o;
    o.x = w0 * b2f((u16)(a.x & 0xFFFF)) + w1 * b2f((u16)(b.x & 0xFFFF));
    o.y = w0 * b2f((u16)(a.x >> 16))    + w1 * b2f((u16)(b.x >> 16));
    o.z = w0 * b2f((u16)(a.y & 0xFFFF)) + w1 * b2f((u16)(b.y & 0xFFFF));
    o.w = w0 * b2f((u16)(a.y >> 16))    + w1 * b2f((u16)(b.y >> 16));
    *(float4*)(op + d) = o;
  }
}

extern "C" void kernel_launch(void* const* d_in, const int* in_sizes, int n_in,
                              void* d_out, int out_size, void* d_ws, size_t ws_size,
                              hipStream_t stream) {
  const float* x  = (const float*)d_in[0];
  const float* Wr = (const float*)d_in[1];
  const float* br = (const float*)d_in[2];
  const float* W1 = (const float*)d_in[3];
  const float* b1 = (const float*)d_in[4];
  const float* W2 = (const float*)d_in[5];
  const float* b2 = (const float*)d_in[6];
  float* out = (float*)d_out;
  char* ws = (char*)d_ws;

  u16*   W1t  = (u16*)(ws + OFF_W1T);
  u16*   W2t  = (u16*)(ws + OFF_W2T);
  u16*   ybuf = (u16*)(ws + OFF_Y);     // overlays W1t (dead after GEMM1)
  u16*   xb   = (u16*)(ws + OFF_XB);
  u16*   hbuf = (u16*)(ws + OFF_H);
  int*   tos  = (int*)(ws + OFF_TOS);
  int*   sot  = (int*)(ws + OFF_SOT);
  int*   tki  = (int*)(ws + OFF_TKI);
  float* tkw  = (float*)(ws + OFF_TKW);
  int*   cnt  = (int*)(ws + OFF_CNT);
  int*   pof  = (int*)(ws + OFF_POF);
  int*   cur  = (int*)(ws + OFF_CUR);
  int*   nt   = (int*)(ws + OFF_NT);
  int*   te   = (int*)(ws + OFF_TE);
  int*   ts   = (int*)(ws + OFF_TS);

  hipMemsetAsync(tos, 0xFF, (size_t)MAX_SLOTS * sizeof(int), stream);  // -1
  hipMemsetAsync(cnt, 0, 8 * sizeof(int), stream);

  // tiles: NE * (R/256) * (C/64)
  transpose_to_bf16<<<dim3(NE * (DIM / 256) * (HID / 64)), 256, 0, stream>>>(W1, W1t, DIM, HID);
  transpose_to_bf16<<<dim3(NE * (HID / 256) * (DIM / 64)), 256, 0, stream>>>(W2, W2t, HID, DIM);
  convert_x<<<dim3(N_TOK * DIM / (256 * 8)), 256, 0, stream>>>(x, xb);
  router_kernel<<<dim3(N_TOK / 4), 256, 0, stream>>>(x, Wr, br, tki, tkw, cnt);
  plan_kernel<<<dim3(1), 64, 0, stream>>>(cnt, pof, cur, nt, te, ts);
  scatter_kernel<<<dim3(N_TOK / 256), 256, 0, stream>>>(tki, pof, cur, tos, sot);

  // 1D grid, n-block fastest -> XCD-stationary B
  moe_gemm<1><<<dim3((MAX_SLOTS / 128) * (HID / 128)), 256, 0, stream>>>(
      xb, W1t, b1, hbuf, te, ts, nt, tos, DIM, HID, HID / 128);
  moe_gemm<2><<<dim3((MAX_SLOTS / 128) * (DIM / 128)), 256, 0, stream>>>(
      hbuf, W2t, b2, ybuf, te, ts, nt, tos, HID, DIM, DIM / 128);
  combine_kernel<<<dim3(N_TOK / 4), 256, 0, stream>>>(ybuf, sot, tkw, out);
}